// Round 10
// baseline (239.490 us; speedup 1.0000x reference)
//
#include <hip/hip_runtime.h>
#include <math.h>

// R22: PERSISTENT, PLAIN-LOAD HOT PATHS + FINE-GRAINED E HANDOFF.
// R9 (180us, VALU 14.7%): sc1 reads (uncached, compiler-unpipelined) on every
// cross-stage path + 5 global barriers. Fix: (1) all hot READS are plain cached
// loads -- safe because each such buffer is first-touched after its sc1 write
// (dispatch-start acquire invalidated L2; E is ping-ponged EA/EB so gemm-cached
// lines are never rewritten). Writes stay sc1 / memory-side atomics. (2) bupd
// publishes per-r0-tile counters; gemm<1> spins only on the 1-2 tiles it needs
// -> barriers B->C and D->E become producer/consumer overlap. 3 global bars.

// Problem constants
#define R_   1152
#define C_   10
#define D_   16
#define I_   8
#define B_   256
#define N_   160
#define K_   9216
#define KS_  32
#define KC_  288
#define NB_  512      // persistent grid (2 blocks/CU x 256 CU)

// workspace layout (float offsets)
#define OFF_TT    0                      // 2,949,120  tT[c][b][r]
#define OFF_BIJ   2949120                //   184,320  bij[r][n]
#define OFF_EA    3133440                //   184,320  E iter-1
#define OFF_EB    3317760                //   184,320  E iter-2 (ping-pong)
#define OFF_NSA   3502080                //       160  nsumA      (memset 0)
#define OFF_NSB   3502240                //       160  nsumB      (memset 0)
#define OFF_VA    3502400                //    40,960  vaccA[b][n](memset 0)
#define OFF_VB    3543360                //    40,960  vaccB      (memset 0)
#define OFF_VC    3584320                //    40,960  vaccC      (memset 0)
#define OFF_CTA   3625280                //        32  tile counters iter-1 (0)
#define OFF_CTB   3625312                //        32  tile counters iter-2 (0)
#define OFF_BAR   3625344                //        16  barrier counter     (0)
#define MEMSET_F0 OFF_NSA
#define MEMSET_NF (OFF_BAR + 16 - OFF_NSA)

#define SCOPE __HIP_MEMORY_SCOPE_AGENT

__device__ __forceinline__ float aloadf(const float* p) {
    return __hip_atomic_load((float*)p, __ATOMIC_RELAXED, SCOPE);
}
__device__ __forceinline__ int aloadi(const int* p) {
    return __hip_atomic_load((int*)p, __ATOMIC_RELAXED, SCOPE);
}
__device__ __forceinline__ void astore(float* p, float v) {
    __hip_atomic_store(p, v, __ATOMIC_RELAXED, SCOPE);
}

__device__ __forceinline__ float f4c(const float4 v, int i) {
    return i == 0 ? v.x : i == 1 ? v.y : i == 2 ? v.z : v.w;
}

// ---------------------------------------------------------------------------
// Fence-free global barrier (proven R9). Release = vmcnt drain of sc1 stores.
__device__ __forceinline__ void gridbar(int* bar, int goal) {
    asm volatile("s_waitcnt vmcnt(0)" ::: "memory");
    __syncthreads();
    if (threadIdx.x == 0) {
        atomicAdd(bar, 1);
        while (aloadi(bar) < goal) __builtin_amdgcn_s_sleep(16);
    }
    __syncthreads();
    asm volatile("" ::: "memory");
}

// ---------------------------------------------------------------------------
// GEMM body (R1-proven loop). E read PLAIN (EA/EB ping-pong makes it safe);
// when cnt != nullptr, spin until the 1-2 bupd r0-tiles covering rows
// [36ks,36ks+36) are published (count 10 = all c). W/u prefetch issues first.
// Epilogue: memory-side atomicAdd into vacc[b][n].
template <int HASE>
__device__ __forceinline__ void gemm_body(
    const float* __restrict__ u, const float* __restrict__ W,
    const float* __restrict__ E, float* __restrict__ vacc,
    float* smem, int bt, int ks, int tid, const int* cnt) {
    int wave = tid >> 6, lane = tid & 63;
    int ng = lane & 15, bg = lane >> 4;
    int b0 = bt * 16;
    int n0 = ng * 10;

    float acc[4][10];
#pragma unroll
    for (int m = 0; m < 4; ++m)
#pragma unroll
        for (int j = 0; j < 10; ++j) acc[m][j] = 0.0f;

    const float* ubase = u + (size_t)(b0 + bg * 4) * K_ + ks * KC_ + wave * 8;

    float4 wr[5];
    float  ee[5];
    float4 uc[8];
    {
        int r = ks * 36 + wave;
#pragma unroll
        for (int it = 0; it < 5; ++it)      // W prefetch first (covers spin)
            wr[it] = *(const float4*)(W + (size_t)r * 1280 + (it * 64 + lane) * 4);
#pragma unroll
        for (int m = 0; m < 4; ++m)
#pragma unroll
            for (int g = 0; g < 2; ++g)
                uc[m * 2 + g] = *(const float4*)(ubase + (size_t)m * K_ + g * 4);
        if (HASE) {
            int t0 = (ks * 36) >> 6, t1 = (ks * 36 + 35) >> 6;
            if (tid == 0) {
                while (aloadi(&cnt[t0]) < 10) __builtin_amdgcn_s_sleep(8);
                if (t1 != t0)
                    while (aloadi(&cnt[t1]) < 10) __builtin_amdgcn_s_sleep(8);
            }
            __syncthreads();
            asm volatile("" ::: "memory");  // no E-load hoist above the spin
#pragma unroll
            for (int it = 0; it < 5; ++it)
                ee[it] = E[r * N_ + ((it * 64 + lane) >> 1)];   // plain, L2
        }
    }

    int ldsbase = wave * 1280;
    for (int c = 0; c < 9; ++c) {
#pragma unroll
        for (int it = 0; it < 5; ++it) {
            int idx = it * 64 + lane;
            int n = idx >> 1, ih = (idx & 1) * 4;
            float e = HASE ? ee[it] : 1.0f;
            float* q = &smem[ldsbase + ih * 160 + n];
            q[0]   = wr[it].x * e;
            q[160] = wr[it].y * e;
            q[320] = wr[it].z * e;
            q[480] = wr[it].w * e;
        }
        float4 un[8];
        if (c < 8) {
            int r = ks * 36 + (c + 1) * 4 + wave;
#pragma unroll
            for (int it = 0; it < 5; ++it) {
                int idx = it * 64 + lane;
                wr[it] = *(const float4*)(W + (size_t)r * 1280 + idx * 4);
                if (HASE) ee[it] = E[r * N_ + (idx >> 1)];      // plain
            }
#pragma unroll
            for (int m = 0; m < 4; ++m)
#pragma unroll
                for (int g = 0; g < 2; ++g)
                    un[m * 2 + g] = *(const float4*)(ubase + (size_t)m * K_ + (c + 1) * 32 + g * 4);
        }
#pragma unroll
        for (int g = 0; g < 2; ++g) {
#pragma unroll
            for (int t4 = 0; t4 < 4; ++t4) {
                const float* wrow = &smem[ldsbase + (g * 4 + t4) * 160 + n0];
                float w[10];
#pragma unroll
                for (int j = 0; j < 10; j += 2) {
                    float2 ww = *(const float2*)(wrow + j);
                    w[j] = ww.x; w[j + 1] = ww.y;
                }
#pragma unroll
                for (int m = 0; m < 4; ++m) {
                    float uav = f4c(uc[m * 2 + g], t4);
#pragma unroll
                    for (int j = 0; j < 10; ++j)
                        acc[m][j] = fmaf(uav, w[j], acc[m][j]);
                }
            }
        }
        if (c < 8) {
#pragma unroll
            for (int q2 = 0; q2 < 8; ++q2) uc[q2] = un[q2];
        }
    }

    __syncthreads();
#pragma unroll
    for (int m = 0; m < 4; ++m)
#pragma unroll
        for (int j = 0; j < 10; ++j)
            smem[wave * 2560 + (bg * 4 + m) * N_ + n0 + j] = acc[m][j];
    __syncthreads();
    float* outp = vacc + (size_t)b0 * N_;
    for (int f = tid; f < 2560; f += 256)
        atomicAdd(&outp[f], smem[f] + smem[2560 + f] + smem[5120 + f] + smem[7680 + f]);
}

// ---------------------------------------------------------------------------
// tT unit (r-tile 16 x b-tile 32): wsl = sum_d W; tT = wsl . u  (sc1 stores)
__device__ __forceinline__ void tT_unit(const float* __restrict__ u,
                                        const float* __restrict__ W,
                                        float* __restrict__ tT,
                                        int unit, int tid, float* wsl) {
    int r0 = (unit >> 3) * 16;
    int b0 = (unit & 7) * 32;
    __syncthreads();
    for (int q = tid; q < 1280; q += 256) {
        int rr = q / 80, rem = q % 80;
        const float* p = W + (size_t)(r0 + rr) * 1280 + (rem >> 3) * 128 + (rem & 7);
        float s = 0.0f;
#pragma unroll
        for (int d = 0; d < 16; ++d) s += p[d * 8];
        wsl[rr * 84 + rem] = s;
    }
    __syncthreads();
    int r = tid & 15, bgrp = tid >> 4;
    const float* urow = u + (size_t)(r0 + r) * 8;
    float4 ua[2][2];
#pragma unroll
    for (int j = 0; j < 2; ++j) {
        int b = b0 + j * 16 + bgrp;
        const float4* up = (const float4*)(urow + (size_t)b * K_);
        ua[j][0] = up[0]; ua[j][1] = up[1];
    }
#pragma unroll
    for (int c = 0; c < 10; ++c) {
        float4 w0 = *(const float4*)&wsl[r * 84 + c * 8];
        float4 w1 = *(const float4*)&wsl[r * 84 + c * 8 + 4];
#pragma unroll
        for (int j = 0; j < 2; ++j) {
            int b = b0 + j * 16 + bgrp;
            float s = ua[j][0].x * w0.x + ua[j][0].y * w0.y
                    + ua[j][0].z * w0.z + ua[j][0].w * w0.w
                    + ua[j][1].x * w1.x + ua[j][1].y * w1.y
                    + ua[j][1].z * w1.z + ua[j][1].w * w1.w;
            astore(&tT[((size_t)c * B_ + b) * R_ + r0 + r], s);
        }
    }
}

// ---------------------------------------------------------------------------
// bupd: unit (c, r0 tile of 64). ALL reads plain (first-touch-after-sc1-write);
// E/bij via sc1 stores; publish tile counter after vmcnt drain.
__device__ __forceinline__ void bupd_body(
    const float* __restrict__ vacc, const float* __restrict__ tT,
    float* __restrict__ bij, float* __restrict__ E,
    float* __restrict__ nsOut, const float* __restrict__ nsIn,
    int accumulate, int c, int r0, int tid, float* smem, int* cnt) {
    float* vs  = smem;                    // [256][16]
    float* red = smem + 4096;             // [16][258]
    float* exs = smem + 8224;             // [4][16]
    {
        int d = tid & 15, bq = tid >> 4;
        float inv = accumulate ? 1.0f / aloadf(&nsIn[c * 16 + d]) : (1.0f / 1152.0f);
#pragma unroll 4
        for (int bb = 0; bb < 16; ++bb) {
            int b = bq * 16 + bb;
            float s = vacc[(size_t)b * N_ + c * 16 + d] * inv;   // plain
            float sq = s * s;
            vs[b * 16 + d] = sq / (1.0f + sq) * s / (sqrtf(sq) + 1e-5f);
        }
    }
    __syncthreads();

    int rsub = tid & 63, bs = tid >> 6;
    float acc[16];
#pragma unroll
    for (int d = 0; d < 16; ++d) acc[d] = 0.0f;
    const float* tp = tT + (size_t)c * B_ * R_ + r0 + rsub;
#pragma unroll 4
    for (int bb = 0; bb < 64; ++bb) {
        int b = bb * 4 + bs;
        float tv = tp[(size_t)b * R_];                           // plain, L2
        const float4* vrow = (const float4*)(vs + b * 16);
        float4 v0 = vrow[0], v1 = vrow[1], v2 = vrow[2], v3 = vrow[3];
        acc[0]  = fmaf(tv, v0.x, acc[0]);  acc[1]  = fmaf(tv, v0.y, acc[1]);
        acc[2]  = fmaf(tv, v0.z, acc[2]);  acc[3]  = fmaf(tv, v0.w, acc[3]);
        acc[4]  = fmaf(tv, v1.x, acc[4]);  acc[5]  = fmaf(tv, v1.y, acc[5]);
        acc[6]  = fmaf(tv, v1.z, acc[6]);  acc[7]  = fmaf(tv, v1.w, acc[7]);
        acc[8]  = fmaf(tv, v2.x, acc[8]);  acc[9]  = fmaf(tv, v2.y, acc[9]);
        acc[10] = fmaf(tv, v2.z, acc[10]); acc[11] = fmaf(tv, v2.w, acc[11]);
        acc[12] = fmaf(tv, v3.x, acc[12]); acc[13] = fmaf(tv, v3.y, acc[13]);
        acc[14] = fmaf(tv, v3.z, acc[14]); acc[15] = fmaf(tv, v3.w, acc[15]);
    }
#pragma unroll
    for (int d = 0; d < 16; ++d) red[d * 258 + tid] = acc[d];
    __syncthreads();

    int d2 = tid & 15, rg = tid >> 4;
    float exacc = 0.0f;
#pragma unroll
    for (int j = 0; j < 4; ++j) {
        int rr = rg + j * 16;
        const float* rp = red + d2 * 258 + rr;
        float s = (rp[0] + rp[64] + rp[128] + rp[192]) * (1.0f / B_);
        int o = (r0 + rr) * N_ + c * 16 + d2;
        if (accumulate) s += bij[o];                             // plain
        astore(&bij[o], s);
        float ex = __expf(s);
        astore(&E[o], ex);
        exacc += ex;
    }
    exacc += __shfl_down(exacc, 16, 64);
    exacc += __shfl_down(exacc, 32, 64);
    int wv = tid >> 6, ln = tid & 63;
    if (ln < 16) exs[wv * 16 + ln] = exacc;
    __syncthreads();
    if (tid < 16)
        atomicAdd(&nsOut[c * 16 + tid],
                  exs[tid] + exs[16 + tid] + exs[32 + tid] + exs[48 + tid]);
    // publish this (c, r0) tile: E/bij/nsum stores drained, then counter add
    asm volatile("s_waitcnt vmcnt(0)" ::: "memory");
    __syncthreads();
    if (tid == 0) atomicAdd(&cnt[r0 >> 6], 1);
}

// ---------------------------------------------------------------------------
__launch_bounds__(256, 2)
__global__ void digicaps_persistent(const float* __restrict__ u,
                                    const float* __restrict__ W,
                                    float* __restrict__ out,
                                    float* __restrict__ ws) {
    __shared__ float smem[10240];   // 40 KB, reused by every stage
    float* tT    = ws + OFF_TT;
    float* bij   = ws + OFF_BIJ;
    float* EA    = ws + OFF_EA;
    float* EB    = ws + OFF_EB;
    float* nsumA = ws + OFF_NSA;
    float* nsumB = ws + OFF_NSB;
    float* vaccA = ws + OFF_VA;
    float* vaccB = ws + OFF_VB;
    float* vaccC = ws + OFF_VC;
    int*   cntA  = (int*)(ws + OFF_CTA);
    int*   cntB  = (int*)(ws + OFF_CTB);
    int*   bar   = (int*)(ws + OFF_BAR);

    int bid = blockIdx.x, tid = threadIdx.x;
    int bt = bid & 15, ks = bid >> 4;

    // ---- Stage A: gemm<0> -> vaccA; tT (576 units over 512 blocks)
    gemm_body<0>(u, W, nullptr, vaccA, smem, bt, ks, tid, nullptr);
    tT_unit(u, W, tT, bid, tid, smem);
    if (bid < 64) tT_unit(u, W, tT, 512 + bid, tid, smem);
    gridbar(bar, NB_ * 1);

    // ---- Stage B: bupd iter0 -> EA, nsumA; publishes cntA per r0-tile
    if (bid < 180) bupd_body(vaccA, tT, bij, EA, nsumA, nullptr, 0,
                             bid % 10, (bid / 10) * 64, tid, smem, cntA);

    // ---- Stage C: gemm<1> (spins on cntA tiles) -> vaccB
    gemm_body<1>(u, W, EA, vaccB, smem, bt, ks, tid, cntA);
    gridbar(bar, NB_ * 2);

    // ---- Stage D: bupd iter1 (accumulate, /nsumA) -> EB, nsumB; publishes cntB
    if (bid < 180) bupd_body(vaccB, tT, bij, EB, nsumB, nsumA, 1,
                             bid % 10, (bid / 10) * 64, tid, smem, cntB);

    // ---- Stage E: gemm<1> (spins on cntB tiles) -> vaccC
    gemm_body<1>(u, W, EB, vaccC, smem, bt, ks, tid, cntB);
    gridbar(bar, NB_ * 3);

    // ---- Stage F: out = squash(vaccC / nsumB)
    if (bid < 160) {
        int g = bid * 256 + tid;
        float s = vaccC[g] / aloadf(&nsumB[g % N_]);
        float sq = s * s;
        out[g] = sq / (1.0f + sq) * s / (sqrtf(sq) + 1e-5f);
    }
}

// ---------------------------------------------------------------------------
extern "C" void kernel_launch(void* const* d_in, const int* in_sizes, int n_in,
                              void* d_out, int out_size, void* d_ws, size_t ws_size,
                              hipStream_t stream) {
    (void)in_sizes; (void)n_in; (void)out_size; (void)ws_size;
    const float* u = (const float*)d_in[0];
    const float* W = (const float*)d_in[1];
    float* out = (float*)d_out;
    float* ws = (float*)d_ws;

    // zero nsumA/B + vaccA/B/C + tile counters + barrier (contiguous block)
    hipMemsetAsync(ws + MEMSET_F0, 0, MEMSET_NF * sizeof(float), stream);
    hipLaunchKernelGGL(digicaps_persistent, dim3(NB_), dim3(256), 0, stream,
                       u, W, out, ws);
}